// Round 4
// baseline (204.473 us; speedup 1.0000x reference)
//
#include <hip/hip_runtime.h>
#include <stdint.h>

#define IN_DIM  4096
#define OUT_DIM 4096
#define BATCH   4096
#define NACT    32

typedef float f32x4 __attribute__((ext_vector_type(4)));

// ---------------------------------------------------------------------------
// Kernel 1: compress mask+weight -> idx_tab[OUT_DIM][32], w_tab[OUT_DIM][32]
// One block per output row. Deterministic (LDS prefix scan, no atomics).
// ---------------------------------------------------------------------------
__global__ __launch_bounds__(256)
void compress_kernel(const float* __restrict__ weight,
                     const int*   __restrict__ mask,
                     int*         __restrict__ idx_tab,
                     float*       __restrict__ w_tab) {
    const int o = blockIdx.x;
    const int t = threadIdx.x;            // 256 threads
    __shared__ int scan[256];

    const int* mrow = mask + (size_t)o * IN_DIM;
    const int  base = t * 16;             // 16 mask entries per thread

    // vectorized mask read: 4x int4
    int m[16];
    const int4* m4 = (const int4*)(mrow + base);
    #pragma unroll
    for (int j = 0; j < 4; ++j) {
        int4 v = m4[j];
        m[j*4+0] = v.x; m[j*4+1] = v.y; m[j*4+2] = v.z; m[j*4+3] = v.w;
    }
    int c = 0;
    #pragma unroll
    for (int j = 0; j < 16; ++j) c += (m[j] != 0);

    scan[t] = c;
    __syncthreads();
    // Hillis-Steele inclusive scan over 256 entries
    for (int off = 1; off < 256; off <<= 1) {
        int add = (t >= off) ? scan[t - off] : 0;
        __syncthreads();
        scan[t] += add;
        __syncthreads();
    }
    int pos = scan[t] - c;                // exclusive prefix
    for (int j = 0; j < 16; ++j) {
        if (m[j] != 0) {
            int idx = base + j;
            idx_tab[o * NACT + pos] = idx;
            w_tab [o * NACT + pos] = weight[(size_t)o * IN_DIM + idx];
            ++pos;
        }
    }
}

// ---------------------------------------------------------------------------
// Kernel 2: transpose x [BATCH][IN_DIM] -> xT [IN_DIM][BATCH] (f32)
// 64x64 tile, float4 global on BOTH sides, LDS pad-65 (2-way only = free).
// ---------------------------------------------------------------------------
__global__ __launch_bounds__(256)
void transpose_kernel(const float* __restrict__ x, float* __restrict__ xT) {
    __shared__ float tile[64][65];
    const int t  = threadIdx.x;
    const int bi = blockIdx.x;            // batch tile (rows of x)
    const int bj = blockIdx.y;            // in-dim tile (cols of x)

    {   // load: row r = (t>>4)+16p, float4 col c = t&15
        const int c = (t & 15) * 4;
        const int r0 = t >> 4;
        #pragma unroll
        for (int p = 0; p < 4; ++p) {
            int r = r0 + p * 16;
            float4 v = *(const float4*)(x + (size_t)(bi*64 + r) * IN_DIM + bj*64 + c);
            tile[r][c+0] = v.x; tile[r][c+1] = v.y;
            tile[r][c+2] = v.z; tile[r][c+3] = v.w;
        }
    }
    __syncthreads();
    {   // store: output row j (= input col), float4 over batch b4 = t&15
        const int b4 = (t & 15) * 4;
        const int j0 = t >> 4;
        #pragma unroll
        for (int p = 0; p < 4; ++p) {
            int j = j0 + p * 16;
            float4 v;
            v.x = tile[b4+0][j]; v.y = tile[b4+1][j];
            v.z = tile[b4+2][j]; v.w = tile[b4+3][j];
            *(float4*)(xT + (size_t)(bj*64 + j) * BATCH + bi*64 + b4) = v;
        }
    }
}

// ---------------------------------------------------------------------------
// Kernel 3: main sparse matmul using xT.
// Thread = 1 batch x 16 consecutive outputs (acc in 16 VGPRs).
// Block = 256 threads = one 256-batch slab x one 16-output tile.
// Slab xT footprint = 4 MB = one XCD L2; out stores are NON-TEMPORAL so the
// write stream does not evict the slab (round-3 thrash: 3.7x refill).
// idx/w tables for the block's 16 outputs preloaded to LDS (4 KB) once ->
// no per-o serialized scalar-load round trips.
// Grid = 16 slabs * 256 o-tiles; swizzle: XCD x sweeps o-tiles slab-major.
// ---------------------------------------------------------------------------
__global__ __launch_bounds__(256)
void spmm_kernel(const float* __restrict__ xT,
                 const int*   __restrict__ idx_tab,
                 const float* __restrict__ w_tab,
                 const float* __restrict__ bias,
                 float*       __restrict__ out) {
    const int t   = threadIdx.x;
    const int bid = blockIdx.x;           // 4096 blocks
    const int v    = (bid & 7) * 512 + (bid >> 3);   // bijective XCD swizzle
    const int slab = v >> 8;              // 0..15 (slab-major per XCD)
    const int ot   = v & 255;             // o-tile minor
    const int o0   = ot * 16;
    const int b    = slab * 256 + t;      // this thread's batch

    __shared__ int   s_idx[16 * NACT];    // 2 KB
    __shared__ float s_w  [16 * NACT];    // 2 KB
    __shared__ float s_bias[16];

    // cooperative table preload: threads 0-127 load idx (128 int4 = 512 ints),
    // threads 128-255 load w (128 float4 = 512 floats)
    if (t < 128) {
        ((int4*)s_idx)[t] = ((const int4*)(idx_tab + (size_t)o0 * NACT))[t];
    } else {
        ((float4*)s_w)[t - 128] =
            ((const float4*)(w_tab + (size_t)o0 * NACT))[t - 128];
    }
    if (t < 16) s_bias[t] = bias[o0 + t];
    __syncthreads();

    const float* xb = xT + b;             // row i lives at xb[i*BATCH]

    float acc[16];
    #pragma unroll 2
    for (int o = 0; o < 16; ++o) {
        const int*   ip = s_idx + o * NACT;
        const float* wp = s_w   + o * NACT;
        float a0 = 0.f, a1 = 0.f;
        #pragma unroll
        for (int k = 0; k < NACT; k += 2) {
            a0 = fmaf(wp[k],   xb[(size_t)ip[k]   * BATCH], a0);
            a1 = fmaf(wp[k+1], xb[(size_t)ip[k+1] * BATCH], a1);
        }
        acc[o] = (a0 + a1) - s_bias[o];
    }

    float* op = out + (size_t)b * OUT_DIM + o0;     // 64B-aligned, full line
    #pragma unroll
    for (int q = 0; q < 4; ++q) {
        f32x4 r = { acc[q*4+0], acc[q*4+1], acc[q*4+2], acc[q*4+3] };
        __builtin_nontemporal_store(r, (f32x4*)(op + q*4));
    }
}

// ---------------------------------------------------------------------------
// Fallback A (ws >= table only): gathers from x directly (uncoalesced, correct).
// ---------------------------------------------------------------------------
__global__ __launch_bounds__(256)
void spmm_noT_kernel(const float* __restrict__ x,
                     const int*   __restrict__ idx_tab,
                     const float* __restrict__ w_tab,
                     const float* __restrict__ bias,
                     float*       __restrict__ out) {
    const int t   = threadIdx.x;
    const int bid = blockIdx.x;           // 4096 blocks
    const int slab = bid >> 8;
    const int ot   = bid & 255;
    const int o0   = ot * 16;
    const int b    = slab * 256 + t;

    float acc[16];
    #pragma unroll 1
    for (int o = 0; o < 16; ++o) {
        const int*   ip = idx_tab + (size_t)(o0 + o) * NACT;
        const float* wp = w_tab   + (size_t)(o0 + o) * NACT;
        float a = 0.f;
        for (int k = 0; k < NACT; ++k)
            a = fmaf(wp[k], x[(size_t)b * IN_DIM + ip[k]], a);
        acc[o] = a - bias[o0 + o];
    }
    float* op = out + (size_t)b * OUT_DIM + o0;
    #pragma unroll
    for (int q = 0; q < 4; ++q) {
        float4 r; r.x = acc[q*4+0]; r.y = acc[q*4+1];
                  r.z = acc[q*4+2]; r.w = acc[q*4+3];
        *(float4*)(op + q*4) = r;
    }
}

// ---------------------------------------------------------------------------
// Fallback B (tiny ws): block per output row; inline compress into LDS.
// ---------------------------------------------------------------------------
__global__ __launch_bounds__(256)
void naive_kernel(const float* __restrict__ x,
                  const float* __restrict__ weight,
                  const float* __restrict__ bias,
                  const int*   __restrict__ mask,
                  float*       __restrict__ out) {
    const int o = blockIdx.x;
    const int t = threadIdx.x;
    __shared__ int   scan[256];
    __shared__ int   sidx[NACT];
    __shared__ float sw[NACT];

    const int* mrow = mask + (size_t)o * IN_DIM;
    const int  base = t * 16;
    int c = 0;
    #pragma unroll
    for (int j = 0; j < 16; ++j) c += (mrow[base + j] != 0);
    scan[t] = c;
    __syncthreads();
    for (int off = 1; off < 256; off <<= 1) {
        int add = (t >= off) ? scan[t - off] : 0;
        __syncthreads();
        scan[t] += add;
        __syncthreads();
    }
    int pos = scan[t] - c;
    for (int j = 0; j < 16; ++j) {
        if (mrow[base + j] != 0) {
            sidx[pos] = base + j;
            sw[pos]   = weight[(size_t)o * IN_DIM + base + j];
            ++pos;
        }
    }
    __syncthreads();
    const float bo = bias[o];
    for (int b = t; b < BATCH; b += 256) {
        float a = 0.f;
        #pragma unroll
        for (int k = 0; k < NACT; ++k)
            a = fmaf(sw[k], x[(size_t)b * IN_DIM + sidx[k]], a);
        out[(size_t)b * OUT_DIM + o] = a - bo;
    }
}

// ---------------------------------------------------------------------------
extern "C" void kernel_launch(void* const* d_in, const int* in_sizes, int n_in,
                              void* d_out, int out_size, void* d_ws, size_t ws_size,
                              hipStream_t stream) {
    const float* x      = (const float*)d_in[0];
    const float* weight = (const float*)d_in[1];
    const float* bias   = (const float*)d_in[2];
    const int*   mask   = (const int*)  d_in[3];
    float* out = (float*)d_out;

    const size_t TAB_BYTES  = (size_t)OUT_DIM * NACT * (sizeof(int) + sizeof(float)); // 1 MB
    const size_t XT_BYTES   = (size_t)IN_DIM * BATCH * sizeof(float);                 // 64 MB
    const size_t NEED_FULL  = TAB_BYTES + XT_BYTES;

    if (ws_size >= NEED_FULL) {
        int*   idx_tab = (int*)d_ws;
        float* w_tab   = (float*)((char*)d_ws + (size_t)OUT_DIM * NACT * sizeof(int));
        float* xT      = (float*)((char*)d_ws + TAB_BYTES);

        compress_kernel<<<OUT_DIM, 256, 0, stream>>>(weight, mask, idx_tab, w_tab);
        dim3 tgrid(BATCH / 64, IN_DIM / 64);
        transpose_kernel<<<tgrid, 256, 0, stream>>>(x, xT);
        spmm_kernel<<<4096, 256, 0, stream>>>(xT, idx_tab, w_tab, bias, out);
    } else if (ws_size >= TAB_BYTES) {
        int*   idx_tab = (int*)d_ws;
        float* w_tab   = (float*)((char*)d_ws + (size_t)OUT_DIM * NACT * sizeof(int));
        compress_kernel<<<OUT_DIM, 256, 0, stream>>>(weight, mask, idx_tab, w_tab);
        spmm_noT_kernel<<<4096, 256, 0, stream>>>(x, idx_tab, w_tab, bias, out);
    } else {
        naive_kernel<<<OUT_DIM, 256, 0, stream>>>(x, weight, bias, mask, out);
    }
}